// Round 11
// baseline (486.588 us; speedup 1.0000x reference)
//
#include <hip/hip_runtime.h>
#include <stdint.h>

typedef float v4f  __attribute__((ext_vector_type(4)));
typedef float v16f __attribute__((ext_vector_type(16)));
typedef int   v4i  __attribute__((ext_vector_type(4)));

__device__ __forceinline__ void gload_lds16(const void* g, void* l) {
  __builtin_amdgcn_global_load_lds(
      (const __attribute__((address_space(1))) void*)g,
      (__attribute__((address_space(3))) void*)l, 16, 0, 0);
}
__device__ __forceinline__ void gload_lds4(const void* g, void* l) {
  __builtin_amdgcn_global_load_lds(
      (const __attribute__((address_space(1))) void*)g,
      (__attribute__((address_space(3))) void*)l, 4, 0, 0);
}

// ---------------------------------------------------------------------------
// Fused FWHT + MXFP4 quantize, x and w merged into ONE launch.
// Tiling (r10, proven): block = 8 rows x 32 kb. Layouts unchanged:
// packed k-major (kb*R+row)*16; scales dword (kt*2+hik)*R+row, byte ks.
// ---------------------------------------------------------------------------
__global__ __launch_bounds__(256) void quant_fp4_all(
    const float* __restrict__ x, const float* __restrict__ w,
    uint32_t* __restrict__ xpk, uint32_t* __restrict__ wpk,
    uint8_t* __restrict__ xsc, uint8_t* __restrict__ wsc) {
  int bid = blockIdx.x;
  const float* in; uint32_t* packed; uint8_t* scales; int R, rblkbits;
  if (bid < 4096) { in = x; packed = xpk; scales = xsc; R = 8192;  rblkbits = 10; }
  else { bid -= 4096; in = w; packed = wpk; scales = wsc; R = 16384; rblkbits = 11; }

  const int tid = threadIdx.x;
  const int row = ((bid & ((1 << rblkbits) - 1)) << 3) + (tid & 7);
  const int kb  = ((bid >> rblkbits) << 5) + (tid >> 3);

  float v[32];
  const v4f* p = (const v4f*)(in + (size_t)row * 4096 + kb * 32);
#pragma unroll
  for (int c = 0; c < 8; ++c) {
    v4f t = p[c];
    v[c * 4 + 0] = t[0]; v[c * 4 + 1] = t[1];
    v[c * 4 + 2] = t[2]; v[c * 4 + 3] = t[3];
  }
#pragma unroll
  for (int s = 0; s < 5; ++s) {
    const int h = 1 << s;
#pragma unroll
    for (int k = 0; k < 16; ++k) {
      const int i = ((k >> s) << (s + 1)) | (k & (h - 1));
      float a = v[i], b = v[i + h];
      v[i] = a + b; v[i + h] = a - b;
    }
  }
  const float RS = 0.17677669529663687f;  // 32^-0.5
  float amax = 0.0f;
#pragma unroll
  for (int i = 0; i < 32; ++i) {
    v[i] *= RS;
    amax = fmaxf(amax, fabsf(v[i]));
  }
  int E;
  float rscale;
  if (amax > 0.0f) {
    float am = fmaxf(amax, 1e-30f);
    E = (int)((__float_as_uint(am) >> 23) & 255u) - 127;
    rscale = __uint_as_float((uint32_t)(2 - E + 127) << 23);
  } else { E = 2; rscale = 1.0f; }

  uint32_t dw[4] = {0u, 0u, 0u, 0u};
#pragma unroll
  for (int i = 0; i < 32; ++i) {
    float xx = v[i];
    float a = fminf(fabsf(xx) * rscale, 6.0f);
    float rstep = a >= 4.0f ? 0.5f : (a >= 2.0f ? 1.0f : 2.0f);
    float step  = a >= 4.0f ? 2.0f : (a >= 2.0f ? 1.0f : 0.5f);
    float q = rintf(a * rstep) * step;          // RNE onto e2m1 grid
    uint32_t uq = __float_as_uint(q);
    int Eq = (int)(uq >> 23) - 127;
    uint32_t code = (q == 0.0f) ? 0u
                  : (Eq < 0 ? 1u
                            : (((uint32_t)(Eq + 1) << 1) | ((uq >> 22) & 1u)));
    code |= (__float_as_uint(xx) >> 31) << 3;
    dw[i >> 3] |= code << (4 * (i & 7));
  }
  uint4 o; o.x = dw[0]; o.y = dw[1]; o.z = dw[2]; o.w = dw[3];
  *(uint4*)(packed + ((size_t)kb * R + row) * 4) = o;

  const int kt = kb >> 3, hik = kb & 1, ks = (kb >> 1) & 3;
  scales[(size_t)((kt * 2 + hik) * R + row) * 4 + ks] = (uint8_t)(E - 2 + 127);
}

// ---------------------------------------------------------------------------
// MXFP4 GEMM, B^T, 256x256 tile, BK=256, 8 waves (2Mx4N).
// Round-11: B operand bypasses LDS (zero cross-wave reuse) -> direct
// global->reg, double-buffered one tile ahead. A (+A-scales) in a 3-ring
// LDS (104KB). Ledger/tile: [B(t+1):10][Astg(t+2):5], one VMW(5)+barrier.
// ---------------------------------------------------------------------------
#define MFMA4(a, b, c, sa, sb) \
  __builtin_amdgcn_mfma_scale_f32_32x32x64_f8f6f4((a), (b), (c), 4, 4, 0, (sa), 0, (sb))
#define PAD8(x) __builtin_shufflevector((x), (x), 0, 1, 2, 3, -1, -1, -1, -1)
#define BARRIER { asm volatile("" ::: "memory"); __builtin_amdgcn_s_barrier(); asm volatile("" ::: "memory"); }
#define SB0 __builtin_amdgcn_sched_barrier(0)
#define LGKM0 { asm volatile("s_waitcnt lgkmcnt(0)" ::: "memory"); SB0; }
#define VMW(n)  asm volatile("s_waitcnt vmcnt(" #n ")" ::: "memory")

#define RING_SZ 34816   // 32 KB A + 2 KB A-scales

__global__ __launch_bounds__(512, 2) void gemm_fp4_breg(
    const uint8_t* __restrict__ Apk, const uint8_t* __restrict__ Bpk,
    const uint32_t* __restrict__ Asc, const uint32_t* __restrict__ Bsc,
    const float* __restrict__ bias, float* __restrict__ C) {
  const int N = 16384;
  __shared__ uint8_t lds[3 * RING_SZ];

  const int tid = threadIdx.x, lane = tid & 63, wv = tid >> 6;
  const int wm = wv >> 2, wn = wv & 3;           // 2M x 4N waves
  const int hi = lane >> 5, r32 = lane & 31;

  // XCD-aware bijective swizzle (2048 blocks, 8m x 4n clusters per XCD)
  const int bid = blockIdx.x;
  const int xcd = bid & 7, idx = bid >> 3, st = idx >> 5;
  const int mT = ((st & 3) * 8 + (idx & 7)) * 256;
  const int nT = (xcd * 8 + (st >> 2) * 4 + ((idx >> 3) & 3)) * 256;

  // ---- A staging map: 4 x gload16 + 1 x gload4 per thread
  size_t aSrc[4]; int aDst[4];
#pragma unroll
  for (int q = 0; q < 4; ++q) {
    const int c = q * 512 + tid;               // 2048 chunks: kc=c>>8, row=c&255
    aSrc[q] = (size_t)(c >> 8) * 131072 + ((size_t)mT + (c & 255)) * 16;
    aDst[q] = c * 16;
  }
  const int ascFix = ((tid >> 8) & 1) * 8192 + mT + (tid & 255);  // dword idx
  const int ascDst = 32768 + (tid & 511) * 4;

#define ASTG(tt, RG) { \
  _Pragma("unroll") for (int q = 0; q < 4; ++q) \
    gload_lds16(Apk + (size_t)(tt) * 1048576 + aSrc[q], &lds[(RG) + aDst[q]]); \
  gload_lds4(Asc + (size_t)(tt) * 16384 + ascFix, &lds[(RG) + ascDst]); }

  // ---- B direct-load map (10 VMEM ops: 8 x b128 frags + 2 x scale dwords)
  const size_t bColOff = ((size_t)nT + wn * 64 + r32) * 16;       // + nf*512
  const uint32_t* bScBase = Bsc + nT + wn * 64 + r32;             // + nf*32

#define BLOAD(FB, SB, tt) { \
  _Pragma("unroll") for (int j = 0; j < 4; ++j) \
  _Pragma("unroll") for (int nf = 0; nf < 2; ++nf) \
    FB[j * 2 + nf] = *(const v4i*)(Bpk + \
        (size_t)((tt) * 8 + 2 * j + hi) * 262144 + bColOff + nf * 512); \
  _Pragma("unroll") for (int nf = 0; nf < 2; ++nf) \
    SB[nf] = bScBase[(size_t)((tt) * 2 + hi) * 16384 + nf * 32]; }

  // ---- compute-side fixed offsets
  const int aFixed = hi * 4096 + (wm * 128 + r32) * 16;   // + ring + j*8192 + mf*512
  const int sFixed = hi * 1024 + (wm * 128 + r32) * 4;    // + ring + 32768 + mf*128

  v16f acc[4][2] = {};
  v4i fB0[8], fB1[8];
  uint32_t sb0[2], sb1[2];

#define COMPUTE(RG, FB, SB) { \
  const int aA = (RG) + aFixed; \
  const int sA = (RG) + 32768 + sFixed; \
  uint32_t saD[4]; \
  _Pragma("unroll") for (int mf = 0; mf < 4; ++mf) \
    saD[mf] = *(const uint32_t*)&lds[sA + mf * 128]; \
  _Pragma("unroll") for (int j = 0; j < 4; ++j) { \
    v4i fa[4]; \
    _Pragma("unroll") for (int mf = 0; mf < 4; ++mf) \
      fa[mf] = *(const v4i*)&lds[aA + j * 8192 + mf * 512]; \
    LGKM0; \
    __builtin_amdgcn_s_setprio(1); \
    _Pragma("unroll") for (int mf = 0; mf < 4; ++mf) \
    _Pragma("unroll") for (int nf = 0; nf < 2; ++nf) \
      acc[mf][nf] = MFMA4(PAD8(fa[mf]), PAD8(FB[j * 2 + nf]), acc[mf][nf], \
                          (int)((saD[mf] >> (8 * j)) & 255u), \
                          (int)((SB[nf] >> (8 * j)) & 255u)); \
    __builtin_amdgcn_s_setprio(0); \
  } }

  // ---- prologue: A(0)->ring0, A(1)->ring1, B(0)->fB0
  ASTG(0, 0); ASTG(1, RING_SZ); BLOAD(fB0, sb0, 0);
  VMW(0);
  BARRIER;

  int rC = 0;              // ring of tile t
  int rS = 2 * RING_SZ;    // ring of tile t+2
  // ---- main: tiles 0..13 (parity-unrolled x2 for B register sets)
#pragma unroll 1
  for (int i = 0; i < 7; ++i) {
    const int t0 = 2 * i;
    // even tile t0: cur=fB0, next=fB1
    BLOAD(fB1, sb1, t0 + 1); ASTG(t0 + 2, rS); SB0;
    COMPUTE(rC, fB0, sb0);
    VMW(5); BARRIER;
    rC = (rC == 2 * RING_SZ) ? 0 : rC + RING_SZ;
    rS = (rS == 2 * RING_SZ) ? 0 : rS + RING_SZ;
    // odd tile t0+1: cur=fB1, next=fB0
    BLOAD(fB0, sb0, t0 + 2); ASTG(t0 + 3, rS); SB0;
    COMPUTE(rC, fB1, sb1);
    VMW(5); BARRIER;
    rC = (rC == 2 * RING_SZ) ? 0 : rC + RING_SZ;
    rS = (rS == 2 * RING_SZ) ? 0 : rS + RING_SZ;
  }
  // ---- tile 14 (even, cur=fB0): last B prefetch, full drain
  BLOAD(fB1, sb1, 15); SB0;
  COMPUTE(rC, fB0, sb0);
  VMW(0); BARRIER;
  rC = (rC == 2 * RING_SZ) ? 0 : rC + RING_SZ;
  // ---- tile 15 (odd, cur=fB1): no issues
  COMPUTE(rC, fB1, sb1);

  // ---- epilogue: 32x32 C/D layout col=lane&31, row=(q&3)+8*(q>>2)+4*hi
#pragma unroll
  for (int nf = 0; nf < 2; ++nf) {
    const int col = nT + wn * 64 + nf * 32 + r32;
    const float bv = bias[col];
#pragma unroll
    for (int mf = 0; mf < 4; ++mf) {
      const int rbase = mT + wm * 128 + mf * 32 + 4 * hi;
#pragma unroll
      for (int q = 0; q < 16; ++q) {
        const int rowl = (q & 3) + 8 * (q >> 2);
        C[(size_t)(rbase + rowl) * N + col] = acc[mf][nf][q] + bv;
      }
    }
  }
}

// ---------------------------------------------------------------------------
extern "C" void kernel_launch(void* const* d_in, const int* in_sizes, int n_in,
                              void* d_out, int out_size, void* d_ws, size_t ws_size,
                              hipStream_t stream) {
  const float* x    = (const float*)d_in[0];   // 8192 x 4096
  const float* w    = (const float*)d_in[1];   // 16384 x 4096
  const float* bias = (const float*)d_in[2];   // 16384
  float* out = (float*)d_out;                  // 8192 x 16384 fp32

  uint8_t* x_pk = (uint8_t*)d_ws;                        // 16 MB
  uint8_t* w_pk = x_pk + (size_t)16 * 1024 * 1024;       // 32 MB
  uint8_t* x_sc = w_pk + (size_t)32 * 1024 * 1024;       // 1 MB
  uint8_t* w_sc = x_sc + (size_t)1  * 1024 * 1024;       // 2 MB

  quant_fp4_all<<<12288, 256, 0, stream>>>(
      x, w, (uint32_t*)x_pk, (uint32_t*)w_pk, x_sc, w_sc);

  gemm_fp4_breg<<<2048, dim3(512), 0, stream>>>(
      x_pk, w_pk, (const uint32_t*)x_sc, (const uint32_t*)w_sc, bias, out);
}